// Round 3
// baseline (413.039 us; speedup 1.0000x reference)
//
#include <hip/hip_runtime.h>
#include <math.h>

#define HSZ 4096
#define CHUNK 64             // K rows per block
#define COLS_PER_BLOCK 1024  // 256 threads * 4 cols (float4)
#define NBLK_PER_MAT 256     // 4 col-tiles * 64 k-chunks

struct WPtrs { const float* W[8]; };
struct BPtrs { const float* b[8]; };

// --- partial GEMV, atomic accumulate into gates -----------------------------
// gates must be zeroed before launch. Each block checks its own 64-element
// chunk of the input vector; all-zero chunk => skip the 64x1024 weight slab
// (handles h_t == 0 generically, data-dependent).
__global__ __launch_bounds__(256) void lstm_gemv_kernel(
        WPtrs wp, const float* __restrict__ x, const float* __restrict__ hv,
        float* __restrict__ gates) {
    int mat = blockIdx.x >> 8;               // 0..7
    int rem = blockIdx.x & (NBLK_PER_MAT - 1);
    int ct  = rem & 3;                       // column tile
    int kc  = rem >> 2;                      // k chunk
    const float* __restrict__ W = wp.W[mat];
    const float* __restrict__ v = (mat < 4) ? x : hv;

    __shared__ float vs[CHUNK];
    __shared__ int nz;
    int tid = threadIdx.x;
    if (tid == 0) nz = 0;
    __syncthreads();
    if (tid < CHUNK) {                       // wave 0 only (CHUNK == 64)
        float val = v[kc * CHUNK + tid];
        vs[tid] = val;
        if (__any(val != 0.0f) && tid == 0) nz = 1;
    }
    __syncthreads();
    if (!nz) return;                         // whole chunk zero -> skip weights

    int col = ct * COLS_PER_BLOCK + tid * 4;
    const float* Wp = W + (size_t)kc * CHUNK * HSZ + col;

    // Explicit 2-stage software pipeline: 8 float4 loads in flight while the
    // previous 8 are consumed. 2*8*4 = 64 VGPRs of load data -> ~8KB/wave
    // outstanding, vs ~2KB when the compiler schedules it.
    float4 buf[2][8];
#pragma unroll
    for (int u = 0; u < 8; ++u)
        buf[0][u] = *(const float4*)(Wp + (size_t)u * HSZ);

    float4 acc = make_float4(0.f, 0.f, 0.f, 0.f);
#pragma unroll
    for (int b = 0; b < 8; ++b) {
        const int cur = b & 1, nxt = cur ^ 1;
        if (b < 7) {
#pragma unroll
            for (int u = 0; u < 8; ++u)
                buf[nxt][u] = *(const float4*)(Wp + (size_t)((b + 1) * 8 + u) * HSZ);
        }
#pragma unroll
        for (int u = 0; u < 8; ++u) {
            float xv = vs[b * 8 + u];
            acc.x = fmaf(xv, buf[cur][u].x, acc.x);
            acc.y = fmaf(xv, buf[cur][u].y, acc.y);
            acc.z = fmaf(xv, buf[cur][u].z, acc.z);
            acc.w = fmaf(xv, buf[cur][u].w, acc.w);
        }
    }

    float* g = gates + (size_t)(mat & 3) * HSZ + col;
    atomicAdd(g + 0, acc.x);
    atomicAdd(g + 1, acc.y);
    atomicAdd(g + 2, acc.z);
    atomicAdd(g + 3, acc.w);
}

// --- biases + activations + cell update -------------------------------------
__device__ __forceinline__ float sigmoidf_fast(float v) {
    return 1.0f / (1.0f + __expf(-v));
}

__global__ void lstm_final_kernel(const float* __restrict__ gates, BPtrs bp,
                                  const float* __restrict__ c,
                                  float* __restrict__ out) {
    int j = blockIdx.x * 256 + threadIdx.x;   // [0, 4096)
    float ig = gates[j]           + bp.b[0][j] + bp.b[4][j];
    float fg = gates[HSZ + j]     + bp.b[1][j] + bp.b[5][j];
    float gg = gates[2 * HSZ + j] + bp.b[2][j] + bp.b[6][j];
    float og = gates[3 * HSZ + j] + bp.b[3][j] + bp.b[7][j];
    float it = sigmoidf_fast(ig);
    float ft = sigmoidf_fast(fg);
    float gt = tanhf(gg);
    float ot = sigmoidf_fast(og);
    float cn = ft * c[j] + it * gt;
    out[j] = ot * tanhf(cn);
}

extern "C" void kernel_launch(void* const* d_in, const int* in_sizes, int n_in,
                              void* d_out, int out_size, void* d_ws, size_t ws_size,
                              hipStream_t stream) {
    const float* x = (const float*)d_in[0];
    WPtrs wp;
    for (int i = 0; i < 8; ++i) wp.W[i] = (const float*)d_in[1 + i];   // Wii..Who
    BPtrs bp;
    for (int i = 0; i < 8; ++i) bp.b[i] = (const float*)d_in[9 + i];   // bii..bho
    const float* h = (const float*)d_in[17];
    const float* c = (const float*)d_in[18];

    float* gates = (float*)d_ws;                 // 16384 floats, zeroed below

    hipMemsetAsync(gates, 0, 4 * HSZ * sizeof(float), stream);
    lstm_gemv_kernel<<<8 * NBLK_PER_MAT, 256, 0, stream>>>(wp, x, h, gates);
    lstm_final_kernel<<<HSZ / 256, 256, 0, stream>>>(gates, bp, c, (float*)d_out);
}